// Round 1
// baseline (80.708 us; speedup 1.0000x reference)
//
#include <hip/hip_runtime.h>

#define D_SAMPLE 256
#define KCLIENTS 64
#define NH 128   // hidden dim

// ---------------- Kernel 1: per-client attention score ----------------
// grid = 64 blocks (one per client k), block = 128 threads (one per hidden j)
__global__ void lf_scores_kernel(const float* __restrict__ client,
                                 const float* __restrict__ globalt,
                                 const float* __restrict__ W1,
                                 const float* __restrict__ b1,
                                 const float* __restrict__ W2,
                                 const float* __restrict__ b2,
                                 float* __restrict__ scores,
                                 int D) {
    const int k = blockIdx.x;
    const int j = threadIdx.x;  // 0..127

    __shared__ float cs[D_SAMPLE];
    __shared__ float gs[D_SAMPLE];
    __shared__ float partial[2];

    for (int i = j; i < D_SAMPLE; i += NH) {
        cs[i] = client[(size_t)k * D + i];
        gs[i] = globalt[i];
    }
    __syncthreads();

    // h[j] = relu(b1[j] + sum_i attn_in[i] * W1[i][j]), W1 row-major [512][128]
    float h = b1[j];
#pragma unroll 4
    for (int i = 0; i < D_SAMPLE; ++i)
        h = fmaf(cs[i], W1[i * NH + j], h);
#pragma unroll 4
    for (int i = 0; i < D_SAMPLE; ++i)
        h = fmaf(gs[i], W1[(D_SAMPLE + i) * NH + j], h);
    h = fmaxf(h, 0.0f);

    float v = h * W2[j];
    // reduce 128 threads = 2 waves of 64
#pragma unroll
    for (int off = 32; off > 0; off >>= 1)
        v += __shfl_down(v, off, 64);
    if ((j & 63) == 0) partial[j >> 6] = v;
    __syncthreads();
    if (j == 0) scores[k] = partial[0] + partial[1] + b2[0];
}

// ---------------- Kernel 2: softmax over 64 scores ----------------
// grid = 1 block, block = 64 threads
__global__ void lf_softmax_kernel(const float* __restrict__ scores,
                                  float* __restrict__ weights) {
    const int k = threadIdx.x;  // 0..63
    float s = scores[k];
    float m = s;
#pragma unroll
    for (int off = 32; off > 0; off >>= 1)
        m = fmaxf(m, __shfl_xor(m, off, 64));
    float e = __expf(s - m);
    float sum = e;
#pragma unroll
    for (int off = 32; off > 0; off >>= 1)
        sum += __shfl_xor(sum, off, 64);
    weights[k] = e / sum;
}

// ---------------- Kernel 3: weighted fuse (memory-bound) ----------------
// out[d] = 0.5*global[d] + 0.5*sum_k w[k]*client[k][d], float4-vectorized
__global__ void lf_fuse_kernel(const float* __restrict__ client,
                               const float* __restrict__ globalt,
                               const float* __restrict__ weights,
                               float* __restrict__ out,
                               int D4) {
    __shared__ float w[KCLIENTS];
    if (threadIdx.x < KCLIENTS) w[threadIdx.x] = weights[threadIdx.x];
    __syncthreads();

    const float4* __restrict__ c4 = (const float4*)client;
    const float4* __restrict__ g4 = (const float4*)globalt;
    float4* __restrict__ o4 = (float4*)out;

    int idx = blockIdx.x * blockDim.x + threadIdx.x;
    int stride = gridDim.x * blockDim.x;

    for (int d = idx; d < D4; d += stride) {
        float4 acc = make_float4(0.f, 0.f, 0.f, 0.f);
#pragma unroll 8
        for (int k = 0; k < KCLIENTS; ++k) {
            const float wk = w[k];
            const float4 c = c4[(size_t)k * D4 + d];
            acc.x = fmaf(wk, c.x, acc.x);
            acc.y = fmaf(wk, c.y, acc.y);
            acc.z = fmaf(wk, c.z, acc.z);
            acc.w = fmaf(wk, c.w, acc.w);
        }
        const float4 g = g4[d];
        float4 r;
        r.x = 0.5f * g.x + 0.5f * acc.x;
        r.y = 0.5f * g.y + 0.5f * acc.y;
        r.z = 0.5f * g.z + 0.5f * acc.z;
        r.w = 0.5f * g.w + 0.5f * acc.w;
        o4[d] = r;
    }
}

extern "C" void kernel_launch(void* const* d_in, const int* in_sizes, int n_in,
                              void* d_out, int out_size, void* d_ws, size_t ws_size,
                              hipStream_t stream) {
    const float* client  = (const float*)d_in[0];  // [64, D]
    const float* globalt = (const float*)d_in[1];  // [1, D]
    const float* W1      = (const float*)d_in[2];  // [512, 128]
    const float* b1      = (const float*)d_in[3];  // [128]
    const float* W2      = (const float*)d_in[4];  // [128, 1]
    const float* b2      = (const float*)d_in[5];  // [1]
    float* out = (float*)d_out;                    // [1, D]

    const int D = in_sizes[0] / KCLIENTS;          // 1,000,000
    const int D4 = D / 4;                          // 250,000 (D % 4 == 0)

    float* scores  = (float*)d_ws;                 // 64 floats
    float* weights = scores + KCLIENTS;            // 64 floats

    lf_scores_kernel<<<KCLIENTS, NH, 0, stream>>>(client, globalt, W1, b1, W2, b2,
                                                  scores, D);
    lf_softmax_kernel<<<1, 64, 0, stream>>>(scores, weights);

    const int block = 256;
    int grid = (D4 + block - 1) / block;           // 977
    lf_fuse_kernel<<<grid, block, 0, stream>>>(client, globalt, weights, out, D4);
}

// Round 2
// 51.334 us; speedup vs baseline: 1.5722x; 1.5722x over previous
//
#include <hip/hip_runtime.h>

#define D_SAMPLE 256
#define KCLIENTS 64
#define NH 128   // hidden dim

// ---------------- Kernel 1: per-client attention scores ----------------
// grid = 64 blocks (one per client k), block = 512 threads:
// thread t -> (q = t>>7: i-quarter 0..3, j = t&127: hidden unit).
// Each thread does 128 FMAs over its i-quarter; 4 partials combined in LDS.
__global__ void lf_scores_kernel(const float* __restrict__ client,
                                 const float* __restrict__ globalt,
                                 const float* __restrict__ W1,
                                 const float* __restrict__ b1,
                                 const float* __restrict__ W2,
                                 const float* __restrict__ b2,
                                 float* __restrict__ scores,
                                 int D) {
    const int k = blockIdx.x;
    const int t = threadIdx.x;  // 0..511

    __shared__ float attn[2 * D_SAMPLE];   // [cs(256) | gs(256)]
    __shared__ float ph[4][NH];
    __shared__ float red[2];

    if (t < D_SAMPLE)       attn[t] = client[(size_t)k * D + t];
    else                    attn[t] = globalt[t - D_SAMPLE];
    __syncthreads();

    const int q = t >> 7;        // i-quarter
    const int j = t & (NH - 1);  // hidden unit
    const float* __restrict__ w1p = W1 + (size_t)(q * 128) * NH + j;
    const float* __restrict__ xp  = attn + q * 128;

    float acc = 0.0f;
#pragma unroll 8
    for (int i = 0; i < 128; ++i)
        acc = fmaf(xp[i], w1p[(size_t)i * NH], acc);
    ph[q][j] = acc;
    __syncthreads();

    if (t < NH) {
        float h = b1[j] + ph[0][j] + ph[1][j] + ph[2][j] + ph[3][j];
        h = fmaxf(h, 0.0f);
        float v = h * W2[j];
#pragma unroll
        for (int off = 32; off > 0; off >>= 1)
            v += __shfl_down(v, off, 64);
        if ((t & 63) == 0) red[t >> 6] = v;
    }
    __syncthreads();
    if (t == 0) scores[k] = red[0] + red[1] + b2[0];
}

// ---------------- Kernel 2: softmax (in-block) + weighted fuse ----------------
// out[d] = 0.5*global[d] + 0.5*sum_k w[k]*client[k][d], float4-vectorized.
// Each block recomputes the 64-wide softmax from scores (L2-hot, ~200 cycles).
__global__ void lf_fuse_kernel(const float* __restrict__ client,
                               const float* __restrict__ globalt,
                               const float* __restrict__ scores,
                               float* __restrict__ out,
                               int D4) {
    __shared__ float w[KCLIENTS];
    const int t = threadIdx.x;
    if (t < KCLIENTS) {  // wave 0 computes softmax over the 64 scores
        float s = scores[t];
        float m = s;
#pragma unroll
        for (int off = 32; off > 0; off >>= 1)
            m = fmaxf(m, __shfl_xor(m, off, 64));
        float e = __expf(s - m);
        float sum = e;
#pragma unroll
        for (int off = 32; off > 0; off >>= 1)
            sum += __shfl_xor(sum, off, 64);
        w[t] = e / sum;
    }
    __syncthreads();

    const float4* __restrict__ c4 = (const float4*)client;
    const float4* __restrict__ g4 = (const float4*)globalt;
    float4* __restrict__ o4 = (float4*)out;

    int idx = blockIdx.x * blockDim.x + t;
    int stride = gridDim.x * blockDim.x;

    for (int d = idx; d < D4; d += stride) {
        float4 acc = make_float4(0.f, 0.f, 0.f, 0.f);
#pragma unroll 8
        for (int k = 0; k < KCLIENTS; ++k) {
            const float wk = w[k];
            const float4 c = c4[(size_t)k * D4 + d];
            acc.x = fmaf(wk, c.x, acc.x);
            acc.y = fmaf(wk, c.y, acc.y);
            acc.z = fmaf(wk, c.z, acc.z);
            acc.w = fmaf(wk, c.w, acc.w);
        }
        const float4 g = g4[d];
        float4 r;
        r.x = 0.5f * g.x + 0.5f * acc.x;
        r.y = 0.5f * g.y + 0.5f * acc.y;
        r.z = 0.5f * g.z + 0.5f * acc.z;
        r.w = 0.5f * g.w + 0.5f * acc.w;
        o4[d] = r;
    }
}

extern "C" void kernel_launch(void* const* d_in, const int* in_sizes, int n_in,
                              void* d_out, int out_size, void* d_ws, size_t ws_size,
                              hipStream_t stream) {
    const float* client  = (const float*)d_in[0];  // [64, D]
    const float* globalt = (const float*)d_in[1];  // [1, D]
    const float* W1      = (const float*)d_in[2];  // [512, 128]
    const float* b1      = (const float*)d_in[3];  // [128]
    const float* W2      = (const float*)d_in[4];  // [128, 1]
    const float* b2      = (const float*)d_in[5];  // [1]
    float* out = (float*)d_out;                    // [1, D]

    const int D = in_sizes[0] / KCLIENTS;          // 1,000,000
    const int D4 = D / 4;                          // 250,000

    float* scores = (float*)d_ws;                  // 64 floats

    lf_scores_kernel<<<KCLIENTS, 512, 0, stream>>>(client, globalt, W1, b1, W2, b2,
                                                   scores, D);

    const int block = 256;
    int grid = (D4 + block - 1) / block;           // 977
    lf_fuse_kernel<<<grid, block, 0, stream>>>(client, globalt, scores, out, D4);
}